// Round 3
// baseline (1286.457 us; speedup 1.0000x reference)
//
#include <hip/hip_runtime.h>
#include <hip/hip_fp16.h>

#define T_STEPS 512
#define BATCH   64
#define HID     512

// Scan W-row split (chunks of 8 f16 = one float4 = 4 VGPRs):
#define SCH_REG  38                 // register-resident   (152 VGPRs)
#define SCH_LDS  7                  // LDS-resident        (56 KB + 2 KB hbuf)
#define SCH_STRA 13                 // streamed batch A (L2)
#define SCH_STRB 6                  // streamed batch B (L2)  38+7+13+6 = 64

// Workspace layout (full path needs ~34.6 MB):
#define X16_OFF   0u
#define X16_BYTES (16777216u * 2u)          // 32 MB bf16 x
#define WIH_OFF   (X16_OFF + X16_BYTES)
#define WIH_BYTES (262144u * 2u)            // 512 KB bf16 w_ih
#define WHH_OFF   (WIH_OFF + WIH_BYTES)
#define WHH_BYTES (262144u * 2u)            // 512 KB f16 w_hh
#define WS_FULL   (WHH_OFF + WHH_BYTES)

typedef _Float16 half2v  __attribute__((ext_vector_type(2)));
typedef short    short8  __attribute__((ext_vector_type(8)));
typedef float    f32x4   __attribute__((ext_vector_type(4)));
union F4H { float4 f; half2v h[4]; };
union U4I { float4 f; int i[4]; };

__device__ inline float dot2f(half2v a, half2v b, float c) {
    return __builtin_amdgcn_fdot2(a, b, c, false);
}
__device__ inline unsigned short f2bf(float f) {
    unsigned u = __builtin_bit_cast(unsigned, f);
    return (unsigned short)((u + 0x7FFFu + ((u >> 16) & 1u)) >> 16);
}

// ---------------------------------------------------------------------------
// Conversions (re-run every call; ws is re-poisoned by the harness).
// ---------------------------------------------------------------------------
__global__ __launch_bounds__(256) void cvt_f16(const float* __restrict__ w,
                                               __half* __restrict__ o) {
    const int i = (blockIdx.x * 256 + threadIdx.x) * 4;
    float4 v = *(const float4*)(w + i);
    __half2 p0; p0.x = __float2half(v.x); p0.y = __float2half(v.y);
    __half2 p1; p1.x = __float2half(v.z); p1.y = __float2half(v.w);
    *(__half2*)(o + i)     = p0;
    *(__half2*)(o + i + 2) = p1;
}

__global__ __launch_bounds__(256) void cvt_bf16(const float* __restrict__ s,
                                                unsigned short* __restrict__ o) {
    const int i = (blockIdx.x * 256 + threadIdx.x) * 4;
    float4 v = *(const float4*)(s + i);
    ushort4 r = {f2bf(v.x), f2bf(v.y), f2bf(v.z), f2bf(v.w)};
    *(ushort4*)(o + i) = r;
}

// ---------------------------------------------------------------------------
// xproj via bf16 MFMA: out[m][n] = sum_k x[m][k]*w_ih[n][k] + b_ih[n]+b_hh[n]
// M=32768, N=512, K=512. 128x128 tile, 256 thr (4 waves 2x2), BK=32.
// LDS rows stride 40 bf16 (80 B) -> conflict-free b128 frag reads.
// Layouts (guide-verified, m89/m91/m120): A[m=lane&15][k=quad*8+j],
// B[n=lane&15][k=quad*8+j], D: col=lane&15, row=quad*4+reg.
// ---------------------------------------------------------------------------
__global__ __launch_bounds__(256) void xproj_mfma(
    const unsigned short* __restrict__ x16,
    const unsigned short* __restrict__ w16,
    const float* __restrict__ b_ih, const float* __restrict__ b_hh,
    float* __restrict__ out)
{
    __shared__ __align__(16) unsigned short As[128][40];
    __shared__ __align__(16) unsigned short Bs[128][40];

    const int tid   = threadIdx.x;
    const int mBase = blockIdx.y * 128;
    const int nBase = blockIdx.x * 128;
    const int wave  = tid >> 6, lane = tid & 63;
    const int wy    = wave >> 1, wx = wave & 1;
    const int quad  = lane >> 4, l15 = lane & 15;
    const int lr    = tid >> 2;          // 0..63
    const int lk    = (tid & 3) * 8;     // 0,8,16,24

    f32x4 acc[4][4] = {};

    const size_t arow0 = (size_t)(mBase + lr) * 512 + lk;
    const size_t brow0 = (size_t)(nBase + lr) * 512 + lk;

    for (int k0 = 0; k0 < 512; k0 += 32) {
        int4 a0 = *(const int4*)(x16 + arow0 + k0);
        int4 a1 = *(const int4*)(x16 + arow0 + (size_t)64 * 512 + k0);
        int4 b0 = *(const int4*)(w16 + brow0 + k0);
        int4 b1 = *(const int4*)(w16 + brow0 + (size_t)64 * 512 + k0);
        __syncthreads();
        *(int4*)&As[lr][lk]      = a0;
        *(int4*)&As[lr + 64][lk] = a1;
        *(int4*)&Bs[lr][lk]      = b0;
        *(int4*)&Bs[lr + 64][lk] = b1;
        __syncthreads();

        short8 af[4], bf[4];
#pragma unroll
        for (int mt = 0; mt < 4; ++mt)
            af[mt] = *(const short8*)&As[wy * 64 + mt * 16 + l15][quad * 8];
#pragma unroll
        for (int nt = 0; nt < 4; ++nt)
            bf[nt] = *(const short8*)&Bs[wx * 64 + nt * 16 + l15][quad * 8];
#pragma unroll
        for (int mt = 0; mt < 4; ++mt)
#pragma unroll
            for (int nt = 0; nt < 4; ++nt)
                acc[mt][nt] = __builtin_amdgcn_mfma_f32_16x16x32_bf16(
                    af[mt], bf[nt], acc[mt][nt], 0, 0, 0);
    }

    float bias[4]; int coln[4];
#pragma unroll
    for (int nt = 0; nt < 4; ++nt) {
        coln[nt] = nBase + wx * 64 + nt * 16 + l15;
        bias[nt] = b_ih[coln[nt]] + b_hh[coln[nt]];
    }
#pragma unroll
    for (int mt = 0; mt < 4; ++mt)
#pragma unroll
        for (int r = 0; r < 4; ++r) {
            const int row = mBase + wy * 64 + mt * 16 + quad * 4 + r;
#pragma unroll
            for (int nt = 0; nt < 4; ++nt)
                out[(size_t)row * 512 + coln[nt]] = acc[mt][nt][r] + bias[nt];
        }
}

// ---------------------------------------------------------------------------
// Fallback fp32 xproj (R2 kernel).
// ---------------------------------------------------------------------------
__global__ __launch_bounds__(256) void xproj_gemm(
    const float* __restrict__ x, const float* __restrict__ w_ih,
    const float* __restrict__ b_ih, const float* __restrict__ b_hh,
    float* __restrict__ out)
{
    __shared__ __align__(16) float As[16][68];
    __shared__ __align__(16) float Bs[16][68];

    const int tid   = threadIdx.x;
    const int tx    = tid & 15;
    const int ty    = tid >> 4;
    const int mBase = blockIdx.y * 64;
    const int nBase = blockIdx.x * 64;
    const int ldr   = tid >> 2;
    const int ldk   = (tid & 3) * 4;

    float acc[4][4] = {};
    const float* aptr = x    + (size_t)(mBase + ldr) * 512 + ldk;
    const float* bptr = w_ih + (size_t)(nBase + ldr) * 512 + ldk;

    for (int k0 = 0; k0 < 512; k0 += 16) {
        float4 av = *(const float4*)(aptr + k0);
        float4 bv = *(const float4*)(bptr + k0);
        __syncthreads();
        As[ldk + 0][ldr] = av.x; As[ldk + 1][ldr] = av.y;
        As[ldk + 2][ldr] = av.z; As[ldk + 3][ldr] = av.w;
        Bs[ldk + 0][ldr] = bv.x; Bs[ldk + 1][ldr] = bv.y;
        Bs[ldk + 2][ldr] = bv.z; Bs[ldk + 3][ldr] = bv.w;
        __syncthreads();
#pragma unroll
        for (int kk = 0; kk < 16; ++kk) {
            float4 a = *(const float4*)&As[kk][ty * 4];
            float4 b = *(const float4*)&Bs[kk][tx * 4];
            float ar[4] = {a.x, a.y, a.z, a.w};
            float br[4] = {b.x, b.y, b.z, b.w};
#pragma unroll
            for (int i = 0; i < 4; ++i)
#pragma unroll
                for (int j = 0; j < 4; ++j)
                    acc[i][j] = fmaf(ar[i], br[j], acc[i][j]);
        }
    }
    const int n0 = nBase + tx * 4;
    float bias[4];
#pragma unroll
    for (int j = 0; j < 4; ++j) bias[j] = b_ih[n0 + j] + b_hh[n0 + j];
#pragma unroll
    for (int i = 0; i < 4; ++i) {
        const int m = mBase + ty * 4 + i;
        float4 v = {acc[i][0] + bias[0], acc[i][1] + bias[1],
                    acc[i][2] + bias[2], acc[i][3] + bias[3]};
        *(float4*)(out + (size_t)m * 512 + n0) = v;
    }
}

// ---------------------------------------------------------------------------
// Scan v3: h distributed via v_readlane (no LDS broadcast); W 38 reg chunks
// + 7 LDS chunks + 19 L2-streamed; launch_bounds(512,1) -> 256 VGPR budget.
// ---------------------------------------------------------------------------
#define ACCRL(WF, c) do {                                                     \
    F4H ww_; ww_.f = (WF);                                                    \
    a0 = dot2f(ww_.h[0],                                                      \
        __builtin_bit_cast(half2v, __builtin_amdgcn_readlane(hu.i[0], (c))), a0); \
    a1 = dot2f(ww_.h[1],                                                      \
        __builtin_bit_cast(half2v, __builtin_amdgcn_readlane(hu.i[1], (c))), a1); \
    a2 = dot2f(ww_.h[2],                                                      \
        __builtin_bit_cast(half2v, __builtin_amdgcn_readlane(hu.i[2], (c))), a2); \
    a3 = dot2f(ww_.h[3],                                                      \
        __builtin_bit_cast(half2v, __builtin_amdgcn_readlane(hu.i[3], (c))), a3); \
} while (0)

__global__ __launch_bounds__(512, 1) void rnn_scan3(
    const __half* __restrict__ w16, float* __restrict__ out)
{
    __shared__ __align__(16) float4 wlds[HID][SCH_LDS];   // 56 KB
    __shared__ __align__(16) __half hbuf[2][HID];         // 2 KB

    const int b    = blockIdx.x;
    const int j    = threadIdx.x;
    const int lane = j & 63;

    const __half* wrow = w16 + (size_t)j * HID;

    float4 wreg[SCH_REG];
#pragma unroll
    for (int c = 0; c < SCH_REG; ++c)
        wreg[c] = *(const float4*)(wrow + c * 8);
#pragma unroll
    for (int c = 0; c < SCH_LDS; ++c)
        wlds[j][c] = *(const float4*)(wrow + (SCH_REG + c) * 8);

    hbuf[0][j] = __float2half(0.f);
    __syncthreads();

    float* outb = out + (size_t)b * HID + j;
    const size_t stride = (size_t)BATCH * HID;
    const __half* wstr = wrow + (SCH_REG + SCH_LDS) * 8;   // chunks 45..63

    int cur = 0;
    float hn = 0.f;
    float xp_next = outb[0];

    for (int t = 0; t < T_STEPS; ++t) {
        const float xp = xp_next;
        const int tn = (t + 1 < T_STEPS) ? (t + 1) : t;
        xp_next = outb[(size_t)tn * stride];

        // streamed batch A (chunks 45..57)
        float4 wa[SCH_STRA];
#pragma unroll
        for (int c = 0; c < SCH_STRA; ++c)
            wa[c] = *(const float4*)(wstr + c * 8);

        // full h into this wave's lanes: lane holds chunk `lane`
        U4I hu; hu.f = *(const float4*)(&hbuf[cur][lane * 8]);

        float a0 = xp, a1 = 0.f, a2 = 0.f, a3 = 0.f;

#pragma unroll
        for (int c = 0; c < SCH_REG; ++c) ACCRL(wreg[c], c);

#pragma unroll
        for (int c = 0; c < SCH_STRA; ++c)
            ACCRL(wa[c], SCH_REG + SCH_LDS + c);

        // streamed batch B (chunks 58..63); hidden under LDS chunks
        float4 wb[SCH_STRB];
#pragma unroll
        for (int c = 0; c < SCH_STRB; ++c)
            wb[c] = *(const float4*)(wstr + (SCH_STRA + c) * 8);

#pragma unroll
        for (int c = 0; c < SCH_LDS; ++c) {
            float4 wf = wlds[j][c];
            ACCRL(wf, SCH_REG + c);
        }
#pragma unroll
        for (int c = 0; c < SCH_STRB; ++c)
            ACCRL(wb[c], SCH_REG + SCH_LDS + SCH_STRA + c);

        float s = (a0 + a1) + (a2 + a3);
        s = fminf(fmaxf(s, -15.f), 15.f);
        const float e = __expf(2.f * s);
        hn = (e - 1.f) * __builtin_amdgcn_rcpf(e + 1.f);

        outb[(size_t)t * stride] = hn;
        hbuf[cur ^ 1][j] = __float2half(hn);
        __syncthreads();
        cur ^= 1;
    }
    out[(size_t)T_STEPS * stride + (size_t)b * HID + j] = hn;
}

// ---------------------------------------------------------------------------
// Last-resort fp32 scan (no workspace needed).
// ---------------------------------------------------------------------------
__global__ __launch_bounds__(512) void rnn_scan_f32(const float* __restrict__ w,
                                                    float* __restrict__ out)
{
    __shared__ __align__(16) __half hs[2][HID];
    const int b = blockIdx.x;
    const int j = threadIdx.x;

    hs[0][j] = __float2half(0.f);
    __syncthreads();

    const float* wrow32 = w + (size_t)j * HID;
    float* outb = out + (size_t)b * HID + j;
    int cur = 0;
    float hn = 0.f;

    for (int t = 0; t < T_STEPS; ++t) {
        float a0 = outb[(size_t)t * (BATCH * HID)];
        float a1 = 0.f, a2 = 0.f, a3 = 0.f;
#pragma unroll 4
        for (int k0 = 0; k0 < HID; k0 += 8) {
            float4 w0 = *(const float4*)(wrow32 + k0);
            float4 w1 = *(const float4*)(wrow32 + k0 + 4);
            F4H h; h.f = *(const float4*)(&hs[cur][k0]);
            float2 h0 = __half22float2(*(__half2*)&h.h[0]);
            float2 h1 = __half22float2(*(__half2*)&h.h[1]);
            float2 h2 = __half22float2(*(__half2*)&h.h[2]);
            float2 h3 = __half22float2(*(__half2*)&h.h[3]);
            a0 = fmaf(w0.x, h0.x, a0); a1 = fmaf(w0.y, h0.y, a1);
            a2 = fmaf(w0.z, h1.x, a2); a3 = fmaf(w0.w, h1.y, a3);
            a0 = fmaf(w1.x, h2.x, a0); a1 = fmaf(w1.y, h2.y, a1);
            a2 = fmaf(w1.z, h3.x, a2); a3 = fmaf(w1.w, h3.y, a3);
        }
        hn = tanhf((a0 + a1) + (a2 + a3));
        outb[(size_t)t * (BATCH * HID)] = hn;
        hs[cur ^ 1][j] = __float2half(hn);
        __syncthreads();
        cur ^= 1;
    }
    out[(size_t)T_STEPS * BATCH * HID + (size_t)b * HID + j] = hn;
}

// ---------------------------------------------------------------------------
extern "C" void kernel_launch(void* const* d_in, const int* in_sizes, int n_in,
                              void* d_out, int out_size, void* d_ws, size_t ws_size,
                              hipStream_t stream) {
    const float* x    = (const float*)d_in[0];
    const float* w_ih = (const float*)d_in[1];
    const float* w_hh = (const float*)d_in[2];
    const float* b_ih = (const float*)d_in[3];
    const float* b_hh = (const float*)d_in[4];
    float* out = (float*)d_out;

    char* ws = (char*)d_ws;
    const bool full = ws_size >= (size_t)WS_FULL;
    const bool mid  = ws_size >= (size_t)WHH_BYTES;

    if (full) {
        unsigned short* x16  = (unsigned short*)(ws + X16_OFF);
        unsigned short* wih16 = (unsigned short*)(ws + WIH_OFF);
        __half*         whh16 = (__half*)(ws + WHH_OFF);
        cvt_bf16<<<16384, 256, 0, stream>>>(x, x16);
        cvt_bf16<<<256,   256, 0, stream>>>(w_ih, wih16);
        cvt_f16 <<<256,   256, 0, stream>>>(w_hh, whh16);
        xproj_mfma<<<dim3(4, 256), 256, 0, stream>>>(x16, wih16, b_ih, b_hh, out);
        rnn_scan3<<<BATCH, HID, 0, stream>>>(whh16, out);
    } else if (mid) {
        __half* whh16 = (__half*)ws;
        cvt_f16<<<256, 256, 0, stream>>>(w_hh, whh16);
        xproj_gemm<<<dim3(8, 512), 256, 0, stream>>>(x, w_ih, b_ih, b_hh, out);
        rnn_scan3<<<BATCH, HID, 0, stream>>>(whh16, out);
    } else {
        xproj_gemm<<<dim3(8, 512), 256, 0, stream>>>(x, w_ih, b_ih, b_hh, out);
        rnn_scan_f32<<<BATCH, HID, 0, stream>>>(w_hh, out);
    }
}

// Round 4
// 892.453 us; speedup vs baseline: 1.4415x; 1.4415x over previous
//
#include <hip/hip_runtime.h>
#include <hip/hip_fp16.h>

#define T_STEPS 512
#define BATCH   64
#define HID     512

// Scan W-row split (chunks of 8 f16 = one float4 = 4 VGPRs):
#define SCH_REG  40                 // register-resident   (160 VGPRs @ 256 budget)
#define SCH_LDS  10                 // LDS-resident        (80 KB -> 1 WG/CU!)
#define SCH_SA   7                  // streamed batch A (L2)
#define SCH_SB   7                  // streamed batch B (L2)   40+10+7+7 = 64

// Workspace layout (full path needs ~34.6 MB):
#define X16_OFF   0u
#define X16_BYTES (16777216u * 2u)          // 32 MB bf16 x
#define WIH_OFF   (X16_OFF + X16_BYTES)
#define WIH_BYTES (262144u * 2u)            // 512 KB bf16 w_ih
#define WHH_OFF   (WIH_OFF + WIH_BYTES)
#define WHH_BYTES (262144u * 2u)            // 512 KB f16 w_hh
#define WS_FULL   (WHH_OFF + WHH_BYTES)

typedef _Float16 half2v  __attribute__((ext_vector_type(2)));
typedef short    short8  __attribute__((ext_vector_type(8)));
typedef float    f32x4   __attribute__((ext_vector_type(4)));
union F4H { float4 f; half2v h[4]; };

__device__ inline float dot2f(half2v a, half2v b, float c) {
    return __builtin_amdgcn_fdot2(a, b, c, false);
}
__device__ inline unsigned short f2bf(float f) {
    unsigned u = __builtin_bit_cast(unsigned, f);
    return (unsigned short)((u + 0x7FFFu + ((u >> 16) & 1u)) >> 16);
}

// ---------------------------------------------------------------------------
// Conversions (re-run every call; ws is re-poisoned by the harness).
// ---------------------------------------------------------------------------
__global__ __launch_bounds__(256) void cvt_f16(const float* __restrict__ w,
                                               __half* __restrict__ o) {
    const int i = (blockIdx.x * 256 + threadIdx.x) * 4;
    float4 v = *(const float4*)(w + i);
    __half2 p0; p0.x = __float2half(v.x); p0.y = __float2half(v.y);
    __half2 p1; p1.x = __float2half(v.z); p1.y = __float2half(v.w);
    *(__half2*)(o + i)     = p0;
    *(__half2*)(o + i + 2) = p1;
}

__global__ __launch_bounds__(256) void cvt_bf16(const float* __restrict__ s,
                                                unsigned short* __restrict__ o) {
    const int i = (blockIdx.x * 256 + threadIdx.x) * 4;
    float4 v = *(const float4*)(s + i);
    ushort4 r = {f2bf(v.x), f2bf(v.y), f2bf(v.z), f2bf(v.w)};
    *(ushort4*)(o + i) = r;
}

// ---------------------------------------------------------------------------
// xproj via bf16 MFMA (unchanged from R3 — ~140 us incl. conversions).
// ---------------------------------------------------------------------------
__global__ __launch_bounds__(256) void xproj_mfma(
    const unsigned short* __restrict__ x16,
    const unsigned short* __restrict__ w16,
    const float* __restrict__ b_ih, const float* __restrict__ b_hh,
    float* __restrict__ out)
{
    __shared__ __align__(16) unsigned short As[128][40];
    __shared__ __align__(16) unsigned short Bs[128][40];

    const int tid   = threadIdx.x;
    const int mBase = blockIdx.y * 128;
    const int nBase = blockIdx.x * 128;
    const int wave  = tid >> 6, lane = tid & 63;
    const int wy    = wave >> 1, wx = wave & 1;
    const int quad  = lane >> 4, l15 = lane & 15;
    const int lr    = tid >> 2;
    const int lk    = (tid & 3) * 8;

    f32x4 acc[4][4] = {};

    const size_t arow0 = (size_t)(mBase + lr) * 512 + lk;
    const size_t brow0 = (size_t)(nBase + lr) * 512 + lk;

    for (int k0 = 0; k0 < 512; k0 += 32) {
        int4 a0 = *(const int4*)(x16 + arow0 + k0);
        int4 a1 = *(const int4*)(x16 + arow0 + (size_t)64 * 512 + k0);
        int4 b0 = *(const int4*)(w16 + brow0 + k0);
        int4 b1 = *(const int4*)(w16 + brow0 + (size_t)64 * 512 + k0);
        __syncthreads();
        *(int4*)&As[lr][lk]      = a0;
        *(int4*)&As[lr + 64][lk] = a1;
        *(int4*)&Bs[lr][lk]      = b0;
        *(int4*)&Bs[lr + 64][lk] = b1;
        __syncthreads();

        short8 af[4], bf[4];
#pragma unroll
        for (int mt = 0; mt < 4; ++mt)
            af[mt] = *(const short8*)&As[wy * 64 + mt * 16 + l15][quad * 8];
#pragma unroll
        for (int nt = 0; nt < 4; ++nt)
            bf[nt] = *(const short8*)&Bs[wx * 64 + nt * 16 + l15][quad * 8];
#pragma unroll
        for (int mt = 0; mt < 4; ++mt)
#pragma unroll
            for (int nt = 0; nt < 4; ++nt)
                acc[mt][nt] = __builtin_amdgcn_mfma_f32_16x16x32_bf16(
                    af[mt], bf[nt], acc[mt][nt], 0, 0, 0);
    }

    float bias[4]; int coln[4];
#pragma unroll
    for (int nt = 0; nt < 4; ++nt) {
        coln[nt] = nBase + wx * 64 + nt * 16 + l15;
        bias[nt] = b_ih[coln[nt]] + b_hh[coln[nt]];
    }
#pragma unroll
    for (int mt = 0; mt < 4; ++mt)
#pragma unroll
        for (int r = 0; r < 4; ++r) {
            const int row = mBase + wy * 64 + mt * 16 + quad * 4 + r;
#pragma unroll
            for (int nt = 0; nt < 4; ++nt)
                out[(size_t)row * 512 + coln[nt]] = acc[mt][nt][r] + bias[nt];
        }
}

// ---------------------------------------------------------------------------
// Fallback fp32 xproj.
// ---------------------------------------------------------------------------
__global__ __launch_bounds__(256) void xproj_gemm(
    const float* __restrict__ x, const float* __restrict__ w_ih,
    const float* __restrict__ b_ih, const float* __restrict__ b_hh,
    float* __restrict__ out)
{
    __shared__ __align__(16) float As[16][68];
    __shared__ __align__(16) float Bs[16][68];

    const int tid   = threadIdx.x;
    const int tx    = tid & 15;
    const int ty    = tid >> 4;
    const int mBase = blockIdx.y * 64;
    const int nBase = blockIdx.x * 64;
    const int ldr   = tid >> 2;
    const int ldk   = (tid & 3) * 4;

    float acc[4][4] = {};
    const float* aptr = x    + (size_t)(mBase + ldr) * 512 + ldk;
    const float* bptr = w_ih + (size_t)(nBase + ldr) * 512 + ldk;

    for (int k0 = 0; k0 < 512; k0 += 16) {
        float4 av = *(const float4*)(aptr + k0);
        float4 bv = *(const float4*)(bptr + k0);
        __syncthreads();
        As[ldk + 0][ldr] = av.x; As[ldk + 1][ldr] = av.y;
        As[ldk + 2][ldr] = av.z; As[ldk + 3][ldr] = av.w;
        Bs[ldk + 0][ldr] = bv.x; Bs[ldk + 1][ldr] = bv.y;
        Bs[ldk + 2][ldr] = bv.z; Bs[ldk + 3][ldr] = bv.w;
        __syncthreads();
#pragma unroll
        for (int kk = 0; kk < 16; ++kk) {
            float4 a = *(const float4*)&As[kk][ty * 4];
            float4 b = *(const float4*)&Bs[kk][tx * 4];
            float ar[4] = {a.x, a.y, a.z, a.w};
            float br[4] = {b.x, b.y, b.z, b.w};
#pragma unroll
            for (int i = 0; i < 4; ++i)
#pragma unroll
                for (int j = 0; j < 4; ++j)
                    acc[i][j] = fmaf(ar[i], br[j], acc[i][j]);
        }
    }
    const int n0 = nBase + tx * 4;
    float bias[4];
#pragma unroll
    for (int j = 0; j < 4; ++j) bias[j] = b_ih[n0 + j] + b_hh[n0 + j];
#pragma unroll
    for (int i = 0; i < 4; ++i) {
        const int m = mBase + ty * 4 + i;
        float4 v = {acc[i][0] + bias[0], acc[i][1] + bias[1],
                    acc[i][2] + bias[2], acc[i][3] + bias[3]};
        *(float4*)(out + (size_t)m * 512 + n0) = v;
    }
}

// ---------------------------------------------------------------------------
// Scan v4: LDS > 80 KB forces 1 WG/CU -> backend occupancy target 2 waves/SIMD
// -> 256-VGPR budget -> 40 W-chunks truly register-resident. h distributed by
// LDS wave-uniform broadcast (scan2 style). W-LDS stored [c][j] = conflict-free.
// ---------------------------------------------------------------------------
#define ACC4(WF, G) do {                                        \
    F4H hh_; hh_.f = *(const float4*)(hrow + (G) * 8);          \
    F4H ww_; ww_.f = (WF);                                      \
    a0 = dot2f(ww_.h[0], hh_.h[0], a0);                         \
    a1 = dot2f(ww_.h[1], hh_.h[1], a1);                         \
    a2 = dot2f(ww_.h[2], hh_.h[2], a2);                         \
    a3 = dot2f(ww_.h[3], hh_.h[3], a3); } while (0)

__global__ __launch_bounds__(512)
__attribute__((amdgpu_waves_per_eu(2, 2)))
void rnn_scan4(const __half* __restrict__ w16, float* __restrict__ out)
{
    __shared__ __align__(16) float4 wlds[SCH_LDS][HID];   // 80 KB  ([c][j]!)
    __shared__ __align__(16) __half hbuf[2][HID];         // 2 KB -> 82 KB total

    const int b = blockIdx.x;
    const int j = threadIdx.x;

    const __half* wrow = w16 + (size_t)j * HID;

    // Register-resident W chunks 0..39 (160 VGPRs under the 256 budget)
    float4 wreg[SCH_REG];
#pragma unroll
    for (int c = 0; c < SCH_REG; ++c)
        wreg[c] = *(const float4*)(wrow + c * 8);

    // LDS-resident W chunks 40..49, [c][j] layout (conflict-free b128)
#pragma unroll
    for (int c = 0; c < SCH_LDS; ++c)
        wlds[c][j] = *(const float4*)(wrow + (SCH_REG + c) * 8);

    hbuf[0][j] = __float2half(0.f);
    __syncthreads();

    float* outb = out + (size_t)b * HID + j;
    const size_t stride = (size_t)BATCH * HID;
    const __half* wstr = wrow + (SCH_REG + SCH_LDS) * 8;   // chunks 50..63

    int cur = 0;
    float hn = 0.f;
    float xp_next = outb[0];

    for (int t = 0; t < T_STEPS; ++t) {
        const float xp = xp_next;
        const int tn = (t + 1 < T_STEPS) ? (t + 1) : t;
        xp_next = outb[(size_t)tn * stride];               // prefetch next xp

        const __half* hrow = hbuf[cur];

        // Issue streamed batch A (chunks 50..56)
        float4 wa[SCH_SA];
#pragma unroll
        for (int c = 0; c < SCH_SA; ++c)
            wa[c] = *(const float4*)(wstr + c * 8);

        float a0 = xp, a1 = 0.f, a2 = 0.f, a3 = 0.f;

        // Register part 1 (0..19) — hides batch-A latency
#pragma unroll
        for (int c = 0; c < 20; ++c) ACC4(wreg[c], c);

        // Consume batch A
#pragma unroll
        for (int c = 0; c < SCH_SA; ++c)
            ACC4(wa[c], SCH_REG + SCH_LDS + c);

        // Issue streamed batch B (chunks 57..63)
        float4 wb[SCH_SB];
#pragma unroll
        for (int c = 0; c < SCH_SB; ++c)
            wb[c] = *(const float4*)(wstr + (SCH_SA + c) * 8);

        // Register part 2 (20..39) + LDS chunks (40..49) — hides batch-B
#pragma unroll
        for (int c = 20; c < SCH_REG; ++c) ACC4(wreg[c], c);
#pragma unroll
        for (int c = 0; c < SCH_LDS; ++c) {
            float4 wf = wlds[c][j];
            ACC4(wf, SCH_REG + c);
        }

        // Consume batch B
#pragma unroll
        for (int c = 0; c < SCH_SB; ++c)
            ACC4(wb[c], SCH_REG + SCH_LDS + SCH_SA + c);

        float s = (a0 + a1) + (a2 + a3);
        s = fminf(fmaxf(s, -15.f), 15.f);
        const float e = __expf(2.f * s);
        hn = (e - 1.f) * __builtin_amdgcn_rcpf(e + 1.f);

        outb[(size_t)t * stride] = hn;                     // in-place xp -> h_t
        hbuf[cur ^ 1][j] = __float2half(hn);
        __syncthreads();
        cur ^= 1;
    }
    out[(size_t)T_STEPS * stride + (size_t)b * HID + j] = hn;
}

// ---------------------------------------------------------------------------
// Last-resort fp32 scan (no workspace needed).
// ---------------------------------------------------------------------------
__global__ __launch_bounds__(512) void rnn_scan_f32(const float* __restrict__ w,
                                                    float* __restrict__ out)
{
    __shared__ __align__(16) __half hs[2][HID];
    const int b = blockIdx.x;
    const int j = threadIdx.x;

    hs[0][j] = __float2half(0.f);
    __syncthreads();

    const float* wrow32 = w + (size_t)j * HID;
    float* outb = out + (size_t)b * HID + j;
    int cur = 0;
    float hn = 0.f;

    for (int t = 0; t < T_STEPS; ++t) {
        float a0 = outb[(size_t)t * (BATCH * HID)];
        float a1 = 0.f, a2 = 0.f, a3 = 0.f;
#pragma unroll 4
        for (int k0 = 0; k0 < HID; k0 += 8) {
            float4 w0 = *(const float4*)(wrow32 + k0);
            float4 w1 = *(const float4*)(wrow32 + k0 + 4);
            F4H h; h.f = *(const float4*)(&hs[cur][k0]);
            float2 h0 = __half22float2(*(__half2*)&h.h[0]);
            float2 h1 = __half22float2(*(__half2*)&h.h[1]);
            float2 h2 = __half22float2(*(__half2*)&h.h[2]);
            float2 h3 = __half22float2(*(__half2*)&h.h[3]);
            a0 = fmaf(w0.x, h0.x, a0); a1 = fmaf(w0.y, h0.y, a1);
            a2 = fmaf(w0.z, h1.x, a2); a3 = fmaf(w0.w, h1.y, a3);
            a0 = fmaf(w1.x, h2.x, a0); a1 = fmaf(w1.y, h2.y, a1);
            a2 = fmaf(w1.z, h3.x, a2); a3 = fmaf(w1.w, h3.y, a3);
        }
        hn = tanhf((a0 + a1) + (a2 + a3));
        outb[(size_t)t * (BATCH * HID)] = hn;
        hs[cur ^ 1][j] = __float2half(hn);
        __syncthreads();
        cur ^= 1;
    }
    out[(size_t)T_STEPS * BATCH * HID + (size_t)b * HID + j] = hn;
}

// ---------------------------------------------------------------------------
extern "C" void kernel_launch(void* const* d_in, const int* in_sizes, int n_in,
                              void* d_out, int out_size, void* d_ws, size_t ws_size,
                              hipStream_t stream) {
    const float* x    = (const float*)d_in[0];
    const float* w_ih = (const float*)d_in[1];
    const float* w_hh = (const float*)d_in[2];
    const float* b_ih = (const float*)d_in[3];
    const float* b_hh = (const float*)d_in[4];
    float* out = (float*)d_out;

    char* ws = (char*)d_ws;
    const bool full = ws_size >= (size_t)WS_FULL;
    const bool mid  = ws_size >= (size_t)WHH_BYTES;

    if (full) {
        unsigned short* x16   = (unsigned short*)(ws + X16_OFF);
        unsigned short* wih16 = (unsigned short*)(ws + WIH_OFF);
        __half*         whh16 = (__half*)(ws + WHH_OFF);
        cvt_bf16<<<16384, 256, 0, stream>>>(x, x16);
        cvt_bf16<<<256,   256, 0, stream>>>(w_ih, wih16);
        cvt_f16 <<<256,   256, 0, stream>>>(w_hh, whh16);
        xproj_mfma<<<dim3(4, 256), 256, 0, stream>>>(x16, wih16, b_ih, b_hh, out);
        rnn_scan4<<<BATCH, HID, 0, stream>>>(whh16, out);
    } else if (mid) {
        __half* whh16 = (__half*)ws;
        cvt_f16<<<256, 256, 0, stream>>>(w_hh, whh16);
        xproj_gemm<<<dim3(8, 512), 256, 0, stream>>>(x, w_ih, b_ih, b_hh, out);
        rnn_scan4<<<BATCH, HID, 0, stream>>>(whh16, out);
    } else {
        xproj_gemm<<<dim3(8, 512), 256, 0, stream>>>(x, w_ih, b_ih, b_hh, out);
        rnn_scan_f32<<<BATCH, HID, 0, stream>>>(w_hh, out);
    }
}